// Round 1
// baseline (53.284 us; speedup 1.0000x reference)
//
#include <hip/hip_runtime.h>
#include <math.h>

#define DIM 256
#define NLAYERS 64
#define ROWS_PER_WAVE 8

// DPP helpers: wave-wide shift by one lane.
// wave_shl:1 (0x130): lane i receives lane i+1's value; lane 63 invalid -> 0 (bound_ctrl=true)
__device__ __forceinline__ float dpp_shl1_zero(float v) {
    int r = __builtin_amdgcn_update_dpp(0, __float_as_int(v), 0x130, 0xF, 0xF, true);
    return __int_as_float(r);
}
// wave_shr:1 (0x138): lane i receives lane i-1's value; lane 0 invalid -> keeps `oldv` (bound_ctrl=false)
__device__ __forceinline__ float dpp_shr1_keep(float oldv, float v) {
    int r = __builtin_amdgcn_update_dpp(__float_as_int(oldv), __float_as_int(v), 0x138, 0xF, 0xF, false);
    return __int_as_float(r);
}

__global__ __launch_bounds__(1024, 4)
void clements_kernel(const float* __restrict__ x,
                     const float* __restrict__ theta,
                     float* __restrict__ out) {
    // LDS trig table: tbl[l*256 + p*2 + 0] = cos(2*theta[l][p]); +1 = sin(...)
    // Viewed as float4: tbl4[l*64 + t] = (c[2t], s[2t], c[2t+1], s[2t+1])
    __shared__ float tbl[NLAYERS * DIM];  // 64 KB

    const int tid = threadIdx.x;

    // Build trig table cooperatively (8 entries per thread, one-time).
    #pragma unroll
    for (int k = 0; k < 8; ++k) {
        int idx = tid + 1024 * k;         // idx = l*128 + p, 0..8191
        int l = idx >> 7;
        int p = idx & 127;
        float th = theta[idx];
        float s, c;
        sincosf(2.0f * th, &s, &c);
        // Odd-offset layers only use pairs 0..126; make pair 127 the identity so
        // lane 63's cross-pair update passes element 255 through untouched.
        if ((l & 1) && (p == 127)) { c = 1.0f; s = 0.0f; }
        tbl[idx * 2 + 0] = c;
        tbl[idx * 2 + 1] = s;
    }
    __syncthreads();

    const int w = tid >> 6;    // wave id within block (0..15)
    const int t = tid & 63;    // lane id
    const long base = ((long)blockIdx.x * 16 + w) * ROWS_PER_WAVE;

    // Lane t holds elements 4t..4t+3 of ROWS_PER_WAVE rows.
    float e[ROWS_PER_WAVE][4];
    #pragma unroll
    for (int r = 0; r < ROWS_PER_WAVE; ++r) {
        float4 v = ((const float4*)(x + (base + r) * (long)DIM))[t];
        e[r][0] = v.x; e[r][1] = v.y; e[r][2] = v.z; e[r][3] = v.w;
    }

    const float4* tbl4 = (const float4*)tbl;

    #pragma unroll 2
    for (int l = 0; l < NLAYERS; l += 2) {
        // ---- even layer (offset 0): pairs (e0,e1)->theta pair 2t, (e2,e3)->pair 2t+1
        float4 cs = tbl4[(l << 6) + t];
        #pragma unroll
        for (int r = 0; r < ROWS_PER_WAVE; ++r) {
            float a0 = e[r][0], a1 = e[r][1], a2 = e[r][2], a3 = e[r][3];
            e[r][0] = cs.x * a0 + cs.y * a1;   // yi = c*xi + s*xj
            e[r][1] = cs.y * a0 - cs.x * a1;   // yj = s*xi - c*xj
            e[r][2] = cs.z * a2 + cs.w * a3;
            e[r][3] = cs.w * a2 - cs.z * a3;
        }
        // ---- odd layer (offset 1): local pair (e1,e2)->theta pair 2t,
        //      cross pair (e3, next-lane e0)->theta pair 2t+1
        float4 cs1 = tbl4[((l + 1) << 6) + t];
        #pragma unroll
        for (int r = 0; r < ROWS_PER_WAVE; ++r) {
            float a1 = e[r][1], a2 = e[r][2], a3 = e[r][3];
            float n1 = cs1.x * a1 + cs1.y * a2;
            float n2 = cs1.y * a1 - cs1.x * a2;
            float xjn = dpp_shl1_zero(e[r][0]);           // e0 of lane t+1 (lane63: 0)
            float n3  = cs1.z * a3 + cs1.w * xjn;         // lane63: c=1,s=0 -> e3 passthrough
            float snd = cs1.w * a3 - cs1.z * xjn;         // new e0 for lane t+1
            e[r][0] = dpp_shr1_keep(e[r][0], snd);        // lane0 keeps e0 (elem 0 passthrough)
            e[r][1] = n1; e[r][2] = n2; e[r][3] = n3;
        }
    }

    #pragma unroll
    for (int r = 0; r < ROWS_PER_WAVE; ++r) {
        float4 v;
        v.x = e[r][0]; v.y = e[r][1]; v.z = e[r][2]; v.w = e[r][3];
        ((float4*)(out + (base + r) * (long)DIM))[t] = v;
    }
}

extern "C" void kernel_launch(void* const* d_in, const int* in_sizes, int n_in,
                              void* d_out, int out_size, void* d_ws, size_t ws_size,
                              hipStream_t stream) {
    const float* x     = (const float*)d_in[0];
    const float* theta = (const float*)d_in[1];
    float* out = (float*)d_out;
    // 32768 rows / (16 waves * 8 rows) = 256 blocks of 1024 threads.
    hipLaunchKernelGGL(clements_kernel, dim3(256), dim3(1024), 0, stream, x, theta, out);
}